// Round 1
// baseline (94.223 us; speedup 1.0000x reference)
//
#include <hip/hip_runtime.h>

// SimplifiedMambaBlock analysis (carried over from prior session):
//   h_{t} = A_t * h_{t-1}, h_0 = 0, and there is NO additive input term in the
//   scan, so h == 0 for all t. Therefore ssm_out == 0, y = ssm_out * z == 0,
//   out = einsum(0, out_proj_w) + residual == x bit-exactly in fp32.
//   Optimal kernel = copy x -> d_out. 32 MiB each way, ~10.6 us at 6.3 TB/s.
//
// This round's change: hipMemcpyAsync under graph capture became a
// hipGraphMemcpyNode routed to SDMA (~722 GB/s effective, invisible to kernel
// PMC). Replace with an explicit compute-queue float4 copy kernel — the same
// mechanism the harness's fillBuffer uses to hit 6.3 TB/s on these buffers.

__global__ __launch_bounds__(256) void mamba_identity_copy(
    const float4* __restrict__ src, float4* __restrict__ dst, int n4) {
    int i = blockIdx.x * blockDim.x + threadIdx.x;
    const int stride = gridDim.x * blockDim.x;
    // n4 = 2,097,152 float4s; 2048 blocks x 256 threads -> 4 iters/thread,
    // fully coalesced 16 B/lane loads and stores.
    #pragma unroll 4
    for (; i < n4; i += stride) {
        dst[i] = src[i];
    }
}

extern "C" void kernel_launch(void* const* d_in, const int* in_sizes, int n_in,
                              void* d_out, int out_size, void* d_ws, size_t ws_size,
                              hipStream_t stream) {
    const float4* x = reinterpret_cast<const float4*>(d_in[0]);  // (8,2048,512) f32
    float4* out = reinterpret_cast<float4*>(d_out);
    const int n4 = out_size / 4;  // out_size is in floats (8*2048*512)
    const dim3 grid(2048), block(256);
    hipLaunchKernelGGL(mamba_identity_copy, grid, block, 0, stream, x, out, n4);
}